// Round 3
// baseline (3559.990 us; speedup 1.0000x reference)
//
#include <hip/hip_runtime.h>

typedef unsigned short u16;
typedef unsigned int u32;
typedef __attribute__((ext_vector_type(8))) short bf16x8;
typedef __attribute__((ext_vector_type(4))) float f32x4;

__device__ inline u16 f2bf(float x) {
  u32 u = __float_as_uint(x);
  u32 r = (u + 0x7FFFu + ((u >> 16) & 1u)) >> 16;
  return (u16)r;
}
__device__ inline float bf2f(u16 h) { return __uint_as_float(((u32)h) << 16); }
__device__ inline float sigm(float x) { return 1.f / (1.f + __expf(-x)); }
__device__ inline float tanh_s(float x) {
  float ax = fabsf(x);
  float e = __expf(2.f * ax);
  float t = 1.f - 2.f / (e + 1.f);
  return copysignf(t, x);
}

// ---------------- small helpers ----------------
__global__ void cvt_f32_bf16(const float* __restrict__ s, u16* __restrict__ d, int n) {
  int i = (blockIdx.x * 256 + threadIdx.x) * 4;
  if (i < n) {
    float4 f = *(const float4*)&s[i];
    u32 lo = (u32)f2bf(f.x) | ((u32)f2bf(f.y) << 16);
    u32 hi = (u32)f2bf(f.z) | ((u32)f2bf(f.w) << 16);
    uint2 v; v.x = lo; v.y = hi;
    *(uint2*)&d[i] = v;
  }
}

__global__ void bias_add(const float* __restrict__ a, const float* __restrict__ b,
                         float* __restrict__ d, int n) {
  int i = blockIdx.x * 256 + threadIdx.x;
  if (i < n) d[i] = a[i] + b[i];
}

__global__ void zero_u32(u32* __restrict__ p, int n) {
  int i = blockIdx.x * 256 + threadIdx.x;
  if (i < n) p[i] = 0;
}

// ---------------- generic C = A * B^T GEMM (bf16 MFMA) ----------------
// A: [M,K] (f32 if A_F32 else bf16), B: [N,K] bf16 row-major, C: [M,N]
// 128x128 tile, BK=64, 4 waves (2x2), per-wave 64x64 via 4x4 frags of 16x16x32.
// LDS tiles XOR-swizzled (col ^= (row&7)<<3, 8-elem granule) on BOTH write and
// read sides: without it, 128B rows put all 16 rows of a ds_read_b128 on bank 0
// (round-2 counters: SQ_LDS_BANK_CONFLICT = 1.26e7).
template <int A_F32, int OUT_BF16>
__global__ __launch_bounds__(256) void gemm_bt(
    const void* __restrict__ Ap, const u16* __restrict__ Bp,
    const float* __restrict__ bias, void* __restrict__ Cp,
    int K, int lda, int ldb, int ldc) {
  __shared__ u16 Alds[128 * 64];
  __shared__ u16 Blds[128 * 64];
  const int tid = threadIdx.x;
  const int lane = tid & 63;
  const int w = tid >> 6;
  const int wm = w >> 1, wn = w & 1;
  const int m0 = blockIdx.x * 128, n0 = blockIdx.y * 128;
  const int r = lane & 15, kb = lane >> 4;

  f32x4 acc[4][4];
#pragma unroll
  for (int m = 0; m < 4; ++m)
#pragma unroll
    for (int n = 0; n < 4; ++n) acc[m][n] = (f32x4)0.f;

  for (int k0 = 0; k0 < K; k0 += 64) {
#pragma unroll
    for (int p = 0; p < 4; ++p) {
      int ch = p * 256 + tid;
      int row = ch >> 3;
      int col = (ch & 7) * 8;
      int scol = col ^ ((row & 7) << 3);
      if (A_F32) {
        const float* s = (const float*)Ap + (size_t)(m0 + row) * lda + k0 + col;
        float4 f0 = *(const float4*)s;
        float4 f1 = *(const float4*)(s + 4);
        uint4 v;
        v.x = (u32)f2bf(f0.x) | ((u32)f2bf(f0.y) << 16);
        v.y = (u32)f2bf(f0.z) | ((u32)f2bf(f0.w) << 16);
        v.z = (u32)f2bf(f1.x) | ((u32)f2bf(f1.y) << 16);
        v.w = (u32)f2bf(f1.z) | ((u32)f2bf(f1.w) << 16);
        *(uint4*)&Alds[row * 64 + scol] = v;
      } else {
        uint4 v = *(const uint4*)((const u16*)Ap + (size_t)(m0 + row) * lda + k0 + col);
        *(uint4*)&Alds[row * 64 + scol] = v;
      }
      uint4 vb = *(const uint4*)(Bp + (size_t)(n0 + row) * ldb + k0 + col);
      *(uint4*)&Blds[row * 64 + scol] = vb;
    }
    __syncthreads();
#pragma unroll
    for (int ks = 0; ks < 2; ++ks) {
      int kk = ks * 32 + kb * 8;
      bf16x8 af[4], bfr[4];
#pragma unroll
      for (int m = 0; m < 4; ++m) {
        int row = wm * 64 + m * 16 + r;
        af[m] = *(const bf16x8*)&Alds[row * 64 + (kk ^ ((row & 7) << 3))];
      }
#pragma unroll
      for (int n = 0; n < 4; ++n) {
        int row = wn * 64 + n * 16 + r;
        bfr[n] = *(const bf16x8*)&Blds[row * 64 + (kk ^ ((row & 7) << 3))];
      }
#pragma unroll
      for (int m = 0; m < 4; ++m)
#pragma unroll
        for (int n = 0; n < 4; ++n)
          acc[m][n] = __builtin_amdgcn_mfma_f32_16x16x32_bf16(af[m], bfr[n], acc[m][n], 0, 0, 0);
    }
    __syncthreads();
  }

  const int r4 = kb * 4;
#pragma unroll
  for (int m = 0; m < 4; ++m) {
#pragma unroll
    for (int n = 0; n < 4; ++n) {
      int row = m0 + wm * 64 + m * 16 + r4;
      int col = n0 + wn * 64 + n * 16 + (lane & 15);
      float bv = bias[col];
#pragma unroll
      for (int j = 0; j < 4; ++j) {
        float v = acc[m][n][j] + bv;
        if (OUT_BF16)
          ((u16*)Cp)[(size_t)(row + j) * ldc + col] = f2bf(v);
        else
          ((float*)Cp)[(size_t)(row + j) * ldc + col] = v;
      }
    }
  }
}

// ---------------- persistent LSTM recurrence ----------------
// Grid: exactly 256 blocks x 256 threads, 1 block/CU (no LDS, VGPR <= 512 at
// __launch_bounds__(256,1)) => all co-resident, safe to spin.
// Decomposition: group g (=bid&7, XCD-affine) owns batch rows g*64..g*64+63;
// member m (=bid>>3, 0..31) owns hidden cols m*16..m*16+15 (x4 gates).
// Wave w owns batch rows w*16..w*16+15. Per step, per wave: 4 gate accs
// (i,f,g,o) of 16x16, K=512 => 64 MFMA. W_hh slice held in 256 VGPRs for the
// whole kernel; c state in 4 VGPRs per lane; gates land in-lane so the
// elementwise update needs no cross-lane traffic. h exchanged through a
// double-buffered global array + per-group 32-block atomic barrier.
__global__ __launch_bounds__(256, 1) void lstm_persist(
    const u16* __restrict__ xg,   // [b*64+t][2048]
    const u16* __restrict__ Whh,  // [2048][512] bf16
    u16* __restrict__ h2,         // [2][512][512] bf16 double buffer
    u16* __restrict__ hs,         // [b*64+t][512] bf16
    u32* ctr) {                   // [64][8] zero-initialized
  const int tid = threadIdx.x;
  const int lane = tid & 63;
  const int w = tid >> 6;
  const int g = blockIdx.x & 7;   // group: same-XCD heuristic (perf only)
  const int m = blockIdx.x >> 3;  // member within group
  const int b0 = g * 64;
  const int hc0 = m * 16;
  const int col = lane & 15;
  const int q = lane >> 4;

  // Persistent B fragments: Breg[n][kf] = Whh[n*512+hc0+col][kf*32+q*8 .. +8]
  bf16x8 Breg[4][16];
#pragma unroll
  for (int n = 0; n < 4; ++n)
#pragma unroll
    for (int kf = 0; kf < 16; ++kf)
      Breg[n][kf] = *(const bf16x8*)&Whh[((size_t)(n * 512 + hc0 + col)) * 512 + kf * 32 + q * 8];

  float cst[4] = {0.f, 0.f, 0.f, 0.f};
  const int arow = b0 + w * 16 + col;  // batch row this lane loads as A-frag
  const int gr0 = b0 + w * 16 + q * 4; // batch row base for this lane's acc elems

  for (int t = 0; t < 64; ++t) {
    // xg gate preactivations for this lane's 16 acc elements
    float xv[4][4];
#pragma unroll
    for (int j = 0; j < 4; ++j) {
      const u16* xp = xg + ((size_t)(gr0 + j) * 64 + t) * 2048 + hc0 + col;
#pragma unroll
      for (int n = 0; n < 4; ++n) xv[n][j] = bf2f(xp[n * 512]);
    }

    f32x4 acc[4];
#pragma unroll
    for (int n = 0; n < 4; ++n) acc[n] = (f32x4)0.f;

    if (t > 0) {
      const u16* hp = h2 + (size_t)((t - 1) & 1) * (512 * 512) + (size_t)arow * 512;
#pragma unroll
      for (int kf = 0; kf < 16; ++kf) {
        bf16x8 a = *(const bf16x8*)&hp[kf * 32 + q * 8];
#pragma unroll
        for (int n = 0; n < 4; ++n)
          acc[n] = __builtin_amdgcn_mfma_f32_16x16x32_bf16(a, Breg[n][kf], acc[n], 0, 0, 0);
      }
    }

    u16* hw = h2 + (size_t)(t & 1) * (512 * 512);
#pragma unroll
    for (int j = 0; j < 4; ++j) {
      float vi = acc[0][j] + xv[0][j];
      float vf = acc[1][j] + xv[1][j];
      float vg = acc[2][j] + xv[2][j];
      float vo = acc[3][j] + xv[3][j];
      float ii = sigm(vi), ff = sigm(vf), gg = tanh_s(vg), oo = sigm(vo);
      float cn = ff * cst[j] + ii * gg;
      cst[j] = cn;
      u16 hb = f2bf(oo * tanh_s(cn));
      int br = gr0 + j;
      hw[(size_t)br * 512 + hc0 + col] = hb;
      hs[((size_t)br * 64 + t) * 512 + hc0 + col] = hb;
    }

    if (t < 63) {
      __threadfence();    // release: make h writes device-visible
      __syncthreads();
      if (tid == 0) {
        __hip_atomic_fetch_add(&ctr[t * 8 + g], 1u, __ATOMIC_ACQ_REL, __HIP_MEMORY_SCOPE_AGENT);
        while (__hip_atomic_load(&ctr[t * 8 + g], __ATOMIC_ACQUIRE, __HIP_MEMORY_SCOPE_AGENT) < 32u)
          __builtin_amdgcn_s_sleep(4);
      }
      __syncthreads();
      __threadfence();    // acquire: invalidate stale L1/L2 before reading h2
    }
  }
}

// ---------------- launch ----------------
extern "C" void kernel_launch(void* const* d_in, const int* in_sizes, int n_in,
                              void* d_out, int out_size, void* d_ws, size_t ws_size,
                              hipStream_t stream) {
  (void)in_sizes; (void)n_in; (void)out_size; (void)ws_size;
  const float* msg   = (const float*)d_in[0];  // [512,64,1024]
  const float* W_emb = (const float*)d_in[1];  // [256,1024]
  const float* b_emb = (const float*)d_in[2];  // [256]
  const float* W_ih  = (const float*)d_in[3];  // [2048,256]
  const float* b_ih  = (const float*)d_in[4];  // [2048]
  const float* W_hh  = (const float*)d_in[5];  // [2048,512]
  const float* b_hh  = (const float*)d_in[6];  // [2048]
  const float* W_ag  = (const float*)d_in[7];  // [256,512]
  const float* b_ag  = (const float*)d_in[8];  // [256]
  float* out = (float*)d_out;                  // [512,64,256]

  char* p = (char*)d_ws;
  u16* Wemb_b = (u16*)p;  p += (size_t)256 * 1024 * 2;
  u16* Wih_b  = (u16*)p;  p += (size_t)2048 * 256 * 2;
  u16* Whh_b  = (u16*)p;  p += (size_t)2048 * 512 * 2;
  u16* Wag_b  = (u16*)p;  p += (size_t)256 * 512 * 2;
  float* bc   = (float*)p; p += (size_t)2048 * 4;
  p = (char*)(((size_t)p + 255) & ~(size_t)255);
  u16* emb_b = (u16*)p;   p += (size_t)32768 * 256 * 2;   // 16 MB
  u16* xg    = (u16*)p;   p += (size_t)32768 * 2048 * 2;  // 128 MB
  u16* hs    = (u16*)p;   p += (size_t)32768 * 512 * 2;   // 32 MB
  u16* h2    = (u16*)p;   p += (size_t)2 * 512 * 512 * 2; // 1 MB
  u32* ctr   = (u32*)p;   p += (size_t)64 * 8 * 4;

  // weight converts (redone every call; ws is re-poisoned by harness)
  cvt_f32_bf16<<<256, 256, 0, stream>>>(W_emb, Wemb_b, 256 * 1024);
  cvt_f32_bf16<<<512, 256, 0, stream>>>(W_ih, Wih_b, 2048 * 256);
  cvt_f32_bf16<<<1024, 256, 0, stream>>>(W_hh, Whh_b, 2048 * 512);
  cvt_f32_bf16<<<128, 256, 0, stream>>>(W_ag, Wag_b, 256 * 512);
  bias_add<<<8, 256, 0, stream>>>(b_ih, b_hh, bc, 2048);
  zero_u32<<<2, 256, 0, stream>>>(ctr, 64 * 8);

  // emb[B*T,256] = msg[B*T,1024] @ W_emb^T + b_emb   (bf16 out)
  gemm_bt<1, 1><<<dim3(256, 2), 256, 0, stream>>>(msg, Wemb_b, b_emb, emb_b,
                                                  1024, 1024, 1024, 256);
  // xg[B*T,2048] = emb @ W_ih^T + (b_ih+b_hh)        (bf16 out)
  gemm_bt<0, 1><<<dim3(256, 16), 256, 0, stream>>>(emb_b, Wih_b, bc, xg,
                                                   256, 256, 256, 2048);
  // persistent recurrence: 64 steps in one kernel
  lstm_persist<<<256, 256, 0, stream>>>(xg, Whh_b, h2, hs, ctr);
  // out[B*T,256] = hs @ W_agent^T + b_agent          (f32 out)
  gemm_bt<0, 0><<<dim3(256, 2), 256, 0, stream>>>(hs, Wag_b, b_ag, out,
                                                  512, 512, 512, 256);
}

// Round 4
// 1132.210 us; speedup vs baseline: 3.1443x; 3.1443x over previous
//
#include <hip/hip_runtime.h>

typedef unsigned short u16;
typedef unsigned int u32;
typedef unsigned long long u64;
typedef __attribute__((ext_vector_type(8))) short bf16x8;
typedef __attribute__((ext_vector_type(4))) float f32x4;

__device__ inline u16 f2bf(float x) {
  u32 u = __float_as_uint(x);
  u32 r = (u + 0x7FFFu + ((u >> 16) & 1u)) >> 16;
  return (u16)r;
}
__device__ inline float bf2f(u16 h) { return __uint_as_float(((u32)h) << 16); }
__device__ inline float sigm(float x) { return 1.f / (1.f + __expf(-x)); }
__device__ inline float tanh_s(float x) {
  float ax = fabsf(x);
  float e = __expf(2.f * ax);
  float t = 1.f - 2.f / (e + 1.f);
  return copysignf(t, x);
}

// ---------------- small helpers ----------------
__global__ void cvt_f32_bf16(const float* __restrict__ s, u16* __restrict__ d, int n) {
  int i = (blockIdx.x * 256 + threadIdx.x) * 4;
  if (i < n) {
    float4 f = *(const float4*)&s[i];
    u32 lo = (u32)f2bf(f.x) | ((u32)f2bf(f.y) << 16);
    u32 hi = (u32)f2bf(f.z) | ((u32)f2bf(f.w) << 16);
    uint2 v; v.x = lo; v.y = hi;
    *(uint2*)&d[i] = v;
  }
}

__global__ void bias_add(const float* __restrict__ a, const float* __restrict__ b,
                         float* __restrict__ d, int n) {
  int i = blockIdx.x * 256 + threadIdx.x;
  if (i < n) d[i] = a[i] + b[i];
}

__global__ void zero_u32(u32* __restrict__ p, int n) {
  int i = blockIdx.x * 256 + threadIdx.x;
  if (i < n) p[i] = 0;
}

// ---------------- generic C = A * B^T GEMM (bf16 MFMA) ----------------
// A: [M,K] (f32 if A_F32 else bf16), B: [N,K] bf16 row-major, C: [M,N]
// 128x128 tile, BK=64, 4 waves (2x2), per-wave 64x64 via 4x4 frags of 16x16x32.
// LDS tiles XOR-swizzled (col ^= (row&7)<<3) on both write and read sides.
template <int A_F32, int OUT_BF16>
__global__ __launch_bounds__(256) void gemm_bt(
    const void* __restrict__ Ap, const u16* __restrict__ Bp,
    const float* __restrict__ bias, void* __restrict__ Cp,
    int K, int lda, int ldb, int ldc) {
  __shared__ u16 Alds[128 * 64];
  __shared__ u16 Blds[128 * 64];
  const int tid = threadIdx.x;
  const int lane = tid & 63;
  const int w = tid >> 6;
  const int wm = w >> 1, wn = w & 1;
  const int m0 = blockIdx.x * 128, n0 = blockIdx.y * 128;
  const int r = lane & 15, kb = lane >> 4;

  f32x4 acc[4][4];
#pragma unroll
  for (int m = 0; m < 4; ++m)
#pragma unroll
    for (int n = 0; n < 4; ++n) acc[m][n] = (f32x4)0.f;

  for (int k0 = 0; k0 < K; k0 += 64) {
#pragma unroll
    for (int p = 0; p < 4; ++p) {
      int ch = p * 256 + tid;
      int row = ch >> 3;
      int col = (ch & 7) * 8;
      int scol = col ^ ((row & 7) << 3);
      if (A_F32) {
        const float* s = (const float*)Ap + (size_t)(m0 + row) * lda + k0 + col;
        float4 f0 = *(const float4*)s;
        float4 f1 = *(const float4*)(s + 4);
        uint4 v;
        v.x = (u32)f2bf(f0.x) | ((u32)f2bf(f0.y) << 16);
        v.y = (u32)f2bf(f0.z) | ((u32)f2bf(f0.w) << 16);
        v.z = (u32)f2bf(f1.x) | ((u32)f2bf(f1.y) << 16);
        v.w = (u32)f2bf(f1.z) | ((u32)f2bf(f1.w) << 16);
        *(uint4*)&Alds[row * 64 + scol] = v;
      } else {
        uint4 v = *(const uint4*)((const u16*)Ap + (size_t)(m0 + row) * lda + k0 + col);
        *(uint4*)&Alds[row * 64 + scol] = v;
      }
      uint4 vb = *(const uint4*)(Bp + (size_t)(n0 + row) * ldb + k0 + col);
      *(uint4*)&Blds[row * 64 + scol] = vb;
    }
    __syncthreads();
#pragma unroll
    for (int ks = 0; ks < 2; ++ks) {
      int kk = ks * 32 + kb * 8;
      bf16x8 af[4], bfr[4];
#pragma unroll
      for (int m = 0; m < 4; ++m) {
        int row = wm * 64 + m * 16 + r;
        af[m] = *(const bf16x8*)&Alds[row * 64 + (kk ^ ((row & 7) << 3))];
      }
#pragma unroll
      for (int n = 0; n < 4; ++n) {
        int row = wn * 64 + n * 16 + r;
        bfr[n] = *(const bf16x8*)&Blds[row * 64 + (kk ^ ((row & 7) << 3))];
      }
#pragma unroll
      for (int m = 0; m < 4; ++m)
#pragma unroll
        for (int n = 0; n < 4; ++n)
          acc[m][n] = __builtin_amdgcn_mfma_f32_16x16x32_bf16(af[m], bfr[n], acc[m][n], 0, 0, 0);
    }
    __syncthreads();
  }

  const int r4 = kb * 4;
#pragma unroll
  for (int m = 0; m < 4; ++m) {
#pragma unroll
    for (int n = 0; n < 4; ++n) {
      int row = m0 + wm * 64 + m * 16 + r4;
      int col = n0 + wn * 64 + n * 16 + (lane & 15);
      float bv = bias[col];
#pragma unroll
      for (int j = 0; j < 4; ++j) {
        float v = acc[m][n][j] + bv;
        if (OUT_BF16)
          ((u16*)Cp)[(size_t)(row + j) * ldc + col] = f2bf(v);
        else
          ((float*)Cp)[(size_t)(row + j) * ldc + col] = v;
      }
    }
  }
}

// ---------------- persistent LSTM recurrence (v2) ----------------
// 256 blocks x 256 threads, co-resident (grid == CU count). Group g=bid&7 owns
// batch rows g*64..+63; member m=bid>>3 owns hidden cols m*16..+15 (x4 gates).
// Wave w: batch rows w*16..+15. Per step/wave: 4 gate accs (16x16), K=512 => 64
// MFMA. Whh read via normal cached loads (L2-resident: nothing invalidates L2
// now). h exchanged via RELAXED agent-scope atomics (bypass non-coherent L2,
// hit the device coherence point) -- no __threadfence, no L2 flush/inv.
// Ordering: s_waitcnt vmcnt(0) before the arrival increment guarantees h
// stores reached the coherence point; consumers' atomic loads after the spin
// exit read fresh data. Counters padded to 128 B per (t,g) to kill the atomic
// hotspot (round-3: 256 pollers on one line => ~52 us/step barrier).
__global__ __launch_bounds__(256, 1) void lstm_persist(
    const u16* __restrict__ xg,   // [b*64+t][2048]
    const u16* __restrict__ Whh,  // [2048][512] bf16
    u16* __restrict__ h2,         // [2][512][512] bf16 double buffer
    u16* __restrict__ hs,         // [b*64+t][512] bf16
    u32* ctr) {                   // [64][8][32] zero-initialized, 128B stride
  const int tid = threadIdx.x;
  const int lane = tid & 63;
  const int w = tid >> 6;
  const int g = blockIdx.x & 7;
  const int m = blockIdx.x >> 3;
  const int b0 = g * 64;
  const int hc0 = m * 16;
  const int col = lane & 15;
  const int q = lane >> 4;

  float cst[4] = {0.f, 0.f, 0.f, 0.f};
  const int arow = b0 + w * 16 + col;   // batch row this lane loads as A-frag
  const int gr0 = b0 + w * 16 + q * 4;  // batch row base for acc elements

  for (int t = 0; t < 64; ++t) {
    // xg gate preactivations for this lane's 16 acc elements
    float xv[4][4];
#pragma unroll
    for (int j = 0; j < 4; ++j) {
      const u16* xp = xg + ((size_t)(gr0 + j) * 64 + t) * 2048 + hc0 + col;
#pragma unroll
      for (int n = 0; n < 4; ++n) xv[n][j] = bf2f(xp[n * 512]);
    }

    f32x4 acc[4];
#pragma unroll
    for (int n = 0; n < 4; ++n) acc[n] = (f32x4)0.f;

    if (t > 0) {
      const u16* hp = h2 + (size_t)((t - 1) & 1) * (512 * 512) + (size_t)arow * 512;
#pragma unroll
      for (int kf = 0; kf < 16; ++kf) {
        union { u64 qq[2]; bf16x8 v; } ua;
        const u64* hq = (const u64*)&hp[kf * 32 + q * 8];
        ua.qq[0] = __hip_atomic_load(&hq[0], __ATOMIC_RELAXED, __HIP_MEMORY_SCOPE_AGENT);
        ua.qq[1] = __hip_atomic_load(&hq[1], __ATOMIC_RELAXED, __HIP_MEMORY_SCOPE_AGENT);
#pragma unroll
        for (int n = 0; n < 4; ++n) {
          bf16x8 bfr = *(const bf16x8*)&Whh[(size_t)(n * 512 + hc0 + col) * 512 + kf * 32 + q * 8];
          acc[n] = __builtin_amdgcn_mfma_f32_16x16x32_bf16(ua.v, bfr, acc[n], 0, 0, 0);
        }
      }
    }

    u16* hw = h2 + (size_t)(t & 1) * (512 * 512);
#pragma unroll
    for (int j = 0; j < 4; ++j) {
      float vi = acc[0][j] + xv[0][j];
      float vf = acc[1][j] + xv[1][j];
      float vg = acc[2][j] + xv[2][j];
      float vo = acc[3][j] + xv[3][j];
      float ii = sigm(vi), ff = sigm(vf), gg = tanh_s(vg), oo = sigm(vo);
      float cn = ff * cst[j] + ii * gg;
      cst[j] = cn;
      u16 hb = f2bf(oo * tanh_s(cn));
      int br = gr0 + j;
      __hip_atomic_store(&hw[(size_t)br * 512 + hc0 + col], hb,
                         __ATOMIC_RELAXED, __HIP_MEMORY_SCOPE_AGENT);
      hs[((size_t)br * 64 + t) * 512 + hc0 + col] = hb;  // read by later kernel
    }

    if (t < 63) {
      asm volatile("s_waitcnt vmcnt(0)" ::: "memory");  // h stores at coherence pt
      __syncthreads();
      if (tid == 0) {
        u32* c = &ctr[(size_t)(t * 8 + g) * 32];
        __hip_atomic_fetch_add(c, 1u, __ATOMIC_RELAXED, __HIP_MEMORY_SCOPE_AGENT);
        while (__hip_atomic_load(c, __ATOMIC_RELAXED, __HIP_MEMORY_SCOPE_AGENT) < 32u)
          __builtin_amdgcn_s_sleep(2);
      }
      __syncthreads();
    }
  }
}

// ---------------- launch ----------------
extern "C" void kernel_launch(void* const* d_in, const int* in_sizes, int n_in,
                              void* d_out, int out_size, void* d_ws, size_t ws_size,
                              hipStream_t stream) {
  (void)in_sizes; (void)n_in; (void)out_size; (void)ws_size;
  const float* msg   = (const float*)d_in[0];  // [512,64,1024]
  const float* W_emb = (const float*)d_in[1];  // [256,1024]
  const float* b_emb = (const float*)d_in[2];  // [256]
  const float* W_ih  = (const float*)d_in[3];  // [2048,256]
  const float* b_ih  = (const float*)d_in[4];  // [2048]
  const float* W_hh  = (const float*)d_in[5];  // [2048,512]
  const float* b_hh  = (const float*)d_in[6];  // [2048]
  const float* W_ag  = (const float*)d_in[7];  // [256,512]
  const float* b_ag  = (const float*)d_in[8];  // [256]
  float* out = (float*)d_out;                  // [512,64,256]

  char* p = (char*)d_ws;
  u16* Wemb_b = (u16*)p;  p += (size_t)256 * 1024 * 2;
  u16* Wih_b  = (u16*)p;  p += (size_t)2048 * 256 * 2;
  u16* Whh_b  = (u16*)p;  p += (size_t)2048 * 512 * 2;
  u16* Wag_b  = (u16*)p;  p += (size_t)256 * 512 * 2;
  float* bc   = (float*)p; p += (size_t)2048 * 4;
  p = (char*)(((size_t)p + 255) & ~(size_t)255);
  u16* emb_b = (u16*)p;   p += (size_t)32768 * 256 * 2;   // 16 MB
  u16* xg    = (u16*)p;   p += (size_t)32768 * 2048 * 2;  // 128 MB
  u16* hs    = (u16*)p;   p += (size_t)32768 * 512 * 2;   // 32 MB
  u16* h2    = (u16*)p;   p += (size_t)2 * 512 * 512 * 2; // 1 MB
  u32* ctr   = (u32*)p;   p += (size_t)64 * 8 * 32 * 4;   // 64 KB padded

  cvt_f32_bf16<<<256, 256, 0, stream>>>(W_emb, Wemb_b, 256 * 1024);
  cvt_f32_bf16<<<512, 256, 0, stream>>>(W_ih, Wih_b, 2048 * 256);
  cvt_f32_bf16<<<1024, 256, 0, stream>>>(W_hh, Whh_b, 2048 * 512);
  cvt_f32_bf16<<<128, 256, 0, stream>>>(W_ag, Wag_b, 256 * 512);
  bias_add<<<8, 256, 0, stream>>>(b_ih, b_hh, bc, 2048);
  zero_u32<<<64, 256, 0, stream>>>(ctr, 64 * 8 * 32);

  // emb[B*T,256] = msg[B*T,1024] @ W_emb^T + b_emb   (bf16 out)
  gemm_bt<1, 1><<<dim3(256, 2), 256, 0, stream>>>(msg, Wemb_b, b_emb, emb_b,
                                                  1024, 1024, 1024, 256);
  // xg[B*T,2048] = emb @ W_ih^T + (b_ih+b_hh)        (bf16 out)
  gemm_bt<0, 1><<<dim3(256, 16), 256, 0, stream>>>(emb_b, Wih_b, bc, xg,
                                                   256, 256, 256, 2048);
  // persistent recurrence: 64 steps in one kernel
  lstm_persist<<<256, 256, 0, stream>>>(xg, Whh_b, h2, hs, ctr);
  // out[B*T,256] = hs @ W_agent^T + b_agent          (f32 out)
  gemm_bt<0, 0><<<dim3(256, 2), 256, 0, stream>>>(hs, Wag_b, b_ag, out,
                                                  512, 512, 512, 256);
}

// Round 8
// 1035.861 us; speedup vs baseline: 3.4367x; 1.0930x over previous
//
#include <hip/hip_runtime.h>

typedef unsigned short u16;
typedef unsigned int u32;
typedef unsigned long long u64;
typedef __attribute__((ext_vector_type(8))) short bf16x8;
typedef __attribute__((ext_vector_type(4))) float f32x4;

__device__ inline u16 f2bf(float x) {
  u32 u = __float_as_uint(x);
  u32 r = (u + 0x7FFFu + ((u >> 16) & 1u)) >> 16;
  return (u16)r;
}
__device__ inline float bf2f(u16 h) { return __uint_as_float(((u32)h) << 16); }
__device__ inline float sigm(float x) { return 1.f / (1.f + __expf(-x)); }
__device__ inline float tanh_s(float x) {
  float ax = fabsf(x);
  float e = __expf(2.f * ax);
  float t = 1.f - 2.f / (e + 1.f);
  return copysignf(t, x);
}

// ---------------- small helpers ----------------
__global__ void cvt_f32_bf16(const float* __restrict__ s, u16* __restrict__ d, int n) {
  int i = (blockIdx.x * 256 + threadIdx.x) * 4;
  if (i < n) {
    float4 f = *(const float4*)&s[i];
    u32 lo = (u32)f2bf(f.x) | ((u32)f2bf(f.y) << 16);
    u32 hi = (u32)f2bf(f.z) | ((u32)f2bf(f.w) << 16);
    uint2 v; v.x = lo; v.y = hi;
    *(uint2*)&d[i] = v;
  }
}

__global__ void bias_add(const float* __restrict__ a, const float* __restrict__ b,
                         float* __restrict__ d, int n) {
  int i = blockIdx.x * 256 + threadIdx.x;
  if (i < n) d[i] = a[i] + b[i];
}

__global__ void zero_u32(u32* __restrict__ p, int n) {
  int i = blockIdx.x * 256 + threadIdx.x;
  if (i < n) p[i] = 0;
}

// ---------------- generic C = A * B^T GEMM (bf16 MFMA) ----------------
// A: [M,K] (f32 if A_F32 else bf16), B: [N,K] bf16 row-major, C: [M,N]
// 128x128 tile, BK=64, 4 waves (2x2), per-wave 64x64 via 4x4 frags of 16x16x32.
// LDS tiles XOR-swizzled (col ^= (row&7)<<3) on write and read (ran clean in
// rounds 2-4). ROWPERM: C row r -> (r&63)*512 + (r>>6)  ([b*64+t] -> [t*512+b]).
template <int A_F32, int OUT_BF16, int ROWPERM>
__global__ __launch_bounds__(256) void gemm_bt(
    const void* __restrict__ Ap, const u16* __restrict__ Bp,
    const float* __restrict__ bias, void* __restrict__ Cp,
    int K, int lda, int ldb, int ldc) {
  __shared__ u16 Alds[128 * 64];
  __shared__ u16 Blds[128 * 64];
  const int tid = threadIdx.x;
  const int lane = tid & 63;
  const int w = tid >> 6;
  const int wm = w >> 1, wn = w & 1;
  const int m0 = blockIdx.x * 128, n0 = blockIdx.y * 128;
  const int r = lane & 15, kb = lane >> 4;

  f32x4 acc[4][4];
#pragma unroll
  for (int m = 0; m < 4; ++m)
#pragma unroll
    for (int n = 0; n < 4; ++n) acc[m][n] = (f32x4)0.f;

  for (int k0 = 0; k0 < K; k0 += 64) {
#pragma unroll
    for (int p = 0; p < 4; ++p) {
      int ch = p * 256 + tid;
      int row = ch >> 3;
      int col = (ch & 7) * 8;
      int scol = col ^ ((row & 7) << 3);
      if (A_F32) {
        const float* s = (const float*)Ap + (size_t)(m0 + row) * lda + k0 + col;
        float4 f0 = *(const float4*)s;
        float4 f1 = *(const float4*)(s + 4);
        uint4 v;
        v.x = (u32)f2bf(f0.x) | ((u32)f2bf(f0.y) << 16);
        v.y = (u32)f2bf(f0.z) | ((u32)f2bf(f0.w) << 16);
        v.z = (u32)f2bf(f1.x) | ((u32)f2bf(f1.y) << 16);
        v.w = (u32)f2bf(f1.z) | ((u32)f2bf(f1.w) << 16);
        *(uint4*)&Alds[row * 64 + scol] = v;
      } else {
        uint4 v = *(const uint4*)((const u16*)Ap + (size_t)(m0 + row) * lda + k0 + col);
        *(uint4*)&Alds[row * 64 + scol] = v;
      }
      uint4 vb = *(const uint4*)(Bp + (size_t)(n0 + row) * ldb + k0 + col);
      *(uint4*)&Blds[row * 64 + scol] = vb;
    }
    __syncthreads();
#pragma unroll
    for (int ks = 0; ks < 2; ++ks) {
      int kk = ks * 32 + kb * 8;
      bf16x8 af[4], bfr[4];
#pragma unroll
      for (int m = 0; m < 4; ++m) {
        int row = wm * 64 + m * 16 + r;
        af[m] = *(const bf16x8*)&Alds[row * 64 + (kk ^ ((row & 7) << 3))];
      }
#pragma unroll
      for (int n = 0; n < 4; ++n) {
        int row = wn * 64 + n * 16 + r;
        bfr[n] = *(const bf16x8*)&Blds[row * 64 + (kk ^ ((row & 7) << 3))];
      }
#pragma unroll
      for (int m = 0; m < 4; ++m)
#pragma unroll
        for (int n = 0; n < 4; ++n)
          acc[m][n] = __builtin_amdgcn_mfma_f32_16x16x32_bf16(af[m], bfr[n], acc[m][n], 0, 0, 0);
    }
    __syncthreads();
  }

  const int r4 = kb * 4;
#pragma unroll
  for (int m = 0; m < 4; ++m) {
#pragma unroll
    for (int n = 0; n < 4; ++n) {
      int row = m0 + wm * 64 + m * 16 + r4;
      int col = n0 + wn * 64 + n * 16 + (lane & 15);
      float bv = bias[col];
#pragma unroll
      for (int j = 0; j < 4; ++j) {
        float v = acc[m][n][j] + bv;
        size_t crow = ROWPERM ? ((size_t)((row + j) & 63) * 512 + ((row + j) >> 6))
                              : (size_t)(row + j);
        if (OUT_BF16)
          ((u16*)Cp)[crow * ldc + col] = f2bf(v);
        else
          ((float*)Cp)[crow * ldc + col] = v;
      }
    }
  }
}

// ---------------- persistent LSTM recurrence (v4.1) ----------------
// Grid: 256 blocks x 256 thr (1 block/CU; shape proven to run in rounds 3-4).
// Group g=bid&7 owns batch rows g*64..+63; member m=bid>>3 owns hid cols
// m*16..+15 (x4 gates). Weight-stationary: member's Whh slice (64 gate-rows x
// 512 = 64 KB) lives in LDS for the whole kernel. Per step: group h-tile
// (64x512, 64 KB) staged into LDS once via relaxed-atomic u64 loads, then
// wave w computes m-frag w (16 batch rows) x 4 gate-frags, K=512 => 64 MFMA,
// gates land IN-LANE => elementwise update needs no cross-lane exchange.
// v4 BUG FIXED: staging loaded/wrote only 64 of each thread's 128-elem chunk
// (tmp[16], 8 granules) -> half of hA was uninitialized LDS -> absmax 2.8e-2.
// Now tmp[32] / 16 granules cover the full chunk.
__global__ __launch_bounds__(256, 1) void lstm_persist(
    const u16* __restrict__ xgT,  // [64][512][2048]
    const u16* __restrict__ Whh,  // [2048][512] bf16
    u16* __restrict__ h2,         // [2][512][512] bf16 double buffer
    u16* __restrict__ hs,         // [b*64+t][512] bf16
    u32* ctr) {                   // [64][8][32] zero-init, 128B stride
  __shared__ u16 Bl[64 * 512];  // Whh slice, rows = gate*16+c, XOR-swizzled
  __shared__ u16 hA[64 * 512];  // h_{t-1} group tile, XOR-swizzled
  const int tid = threadIdx.x;
  const int lane = tid & 63;
  const int w = tid >> 6;
  const int g = blockIdx.x & 7;
  const int m = blockIdx.x >> 3;
  const int b0 = g * 64;
  const int hc0 = m * 16;
  const int r = lane & 15, q = lane >> 4;

  // ---- load Whh slice into LDS once (regular cached loads) ----
  {
    int row = tid >> 2;              // 0..63 = gate*16 + c
    int gg = row >> 4, cc = row & 15;
    int c0 = (tid & 3) * 128;        // this thread's 128-elem chunk
    const u16* src = Whh + (size_t)(gg * 512 + hc0 + cc) * 512 + c0;
#pragma unroll
    for (int i = 0; i < 16; ++i) {   // 16 granules of 8 elems = 128 elems
      int col = c0 + i * 8;
      int scol = col ^ ((row & 7) << 3);
      *(uint4*)&Bl[row * 512 + scol] = *(const uint4*)&src[i * 8];
    }
  }
  __syncthreads();

  float cstate[4] = {0.f, 0.f, 0.f, 0.f};
  // this lane's cells: b = b0 + w*16 + q*4 + j, hid = hc0 + r, gates n=0..3
  const int bl0 = b0 + w * 16 + q * 4;

  // xg preload for t=0
  u16 xv[4][4];
#pragma unroll
  for (int j = 0; j < 4; ++j) {
    const u16* xp = xgT + (size_t)(bl0 + j) * 2048 + hc0 + r;  // t=0 slab
#pragma unroll
    for (int n = 0; n < 4; ++n) xv[j][n] = xp[n * 512];
  }

  for (int t = 0; t < 64; ++t) {
    f32x4 acc[4];
#pragma unroll
    for (int n = 0; n < 4; ++n) acc[n] = (f32x4)0.f;

    if (t > 0) {
      // ---- stage h_{t-1} group tile (64x512) into LDS via atomic loads ----
      {
        int row = tid >> 2;            // 0..63
        int c0 = (tid & 3) * 128;      // 128-elem chunk = 32 u64
        const u64* src = (const u64*)(h2 + (size_t)((t - 1) & 1) * (512 * 512) +
                                      (size_t)(b0 + row) * 512 + c0);
        u64 tmp[32];
#pragma unroll
        for (int i = 0; i < 32; ++i)
          tmp[i] = __hip_atomic_load(&src[i], __ATOMIC_RELAXED, __HIP_MEMORY_SCOPE_AGENT);
#pragma unroll
        for (int i = 0; i < 16; ++i) {  // 16 granules of 8 elems (2 u64 each)
          int col = c0 + i * 8;
          int scol = col ^ ((row & 7) << 3);
          u64* dst = (u64*)&hA[row * 512 + scol];
          dst[0] = tmp[i * 2];
          dst[1] = tmp[i * 2 + 1];
        }
      }
      __syncthreads();

      // ---- MFMA: wave w computes rows w*16..+15 x 4 gate-frags, K=512 ----
#pragma unroll
      for (int kf = 0; kf < 16; ++kf) {
        int k = kf * 32 + q * 8;
        int scol = k ^ ((r & 7) << 3);
        bf16x8 a = *(const bf16x8*)&hA[(w * 16 + r) * 512 + scol];
#pragma unroll
        for (int n = 0; n < 4; ++n) {
          bf16x8 b = *(const bf16x8*)&Bl[(n * 16 + r) * 512 + scol];
          acc[n] = __builtin_amdgcn_mfma_f32_16x16x32_bf16(a, b, acc[n], 0, 0, 0);
        }
      }
    }

    // ---- elementwise update: all 4 gates of each cell are in-lane ----
    u16* hw = h2 + (size_t)(t & 1) * (512 * 512);
#pragma unroll
    for (int j = 0; j < 4; ++j) {
      float vi = acc[0][j] + bf2f(xv[j][0]);
      float vf = acc[1][j] + bf2f(xv[j][1]);
      float vg = acc[2][j] + bf2f(xv[j][2]);
      float vo = acc[3][j] + bf2f(xv[j][3]);
      float ii = sigm(vi), ff = sigm(vf), gg = tanh_s(vg), oo = sigm(vo);
      float cn = ff * cstate[j] + ii * gg;
      cstate[j] = cn;
      u16 hb = f2bf(oo * tanh_s(cn));
      int br = bl0 + j;
      __hip_atomic_store(&hw[(size_t)br * 512 + hc0 + r], hb,
                         __ATOMIC_RELAXED, __HIP_MEMORY_SCOPE_AGENT);
      hs[((size_t)br * 64 + t) * 512 + hc0 + r] = hb;
    }

    if (t < 63) {
      // prefetch next step's xg while h stores drain
      const u16* xb2 = xgT + (size_t)(t + 1) * 512 * 2048;
#pragma unroll
      for (int j = 0; j < 4; ++j) {
        const u16* xp = xb2 + (size_t)(bl0 + j) * 2048 + hc0 + r;
#pragma unroll
        for (int n = 0; n < 4; ++n) xv[j][n] = xp[n * 512];
      }
      asm volatile("s_waitcnt vmcnt(0)" ::: "memory");  // h stores at coherence pt
      __syncthreads();  // also: MFMA reads of hA done before next-step staging
      if (tid == 0) {
        u32* c = &ctr[(size_t)(t * 8 + g) * 32];
        __hip_atomic_fetch_add(c, 1u, __ATOMIC_RELAXED, __HIP_MEMORY_SCOPE_AGENT);
        while (__hip_atomic_load(c, __ATOMIC_RELAXED, __HIP_MEMORY_SCOPE_AGENT) < 32u)
          __builtin_amdgcn_s_sleep(2);
      }
      __syncthreads();
    }
  }
}

// ---------------- launch ----------------
extern "C" void kernel_launch(void* const* d_in, const int* in_sizes, int n_in,
                              void* d_out, int out_size, void* d_ws, size_t ws_size,
                              hipStream_t stream) {
  (void)in_sizes; (void)n_in; (void)out_size; (void)ws_size;
  const float* msg   = (const float*)d_in[0];  // [512,64,1024]
  const float* W_emb = (const float*)d_in[1];  // [256,1024]
  const float* b_emb = (const float*)d_in[2];  // [256]
  const float* W_ih  = (const float*)d_in[3];  // [2048,256]
  const float* b_ih  = (const float*)d_in[4];  // [2048]
  const float* W_hh  = (const float*)d_in[5];  // [2048,512]
  const float* b_hh  = (const float*)d_in[6];  // [2048]
  const float* W_ag  = (const float*)d_in[7];  // [256,512]
  const float* b_ag  = (const float*)d_in[8];  // [256]
  float* out = (float*)d_out;                  // [512,64,256]

  char* p = (char*)d_ws;
  u16* Wemb_b = (u16*)p;  p += (size_t)256 * 1024 * 2;
  u16* Wih_b  = (u16*)p;  p += (size_t)2048 * 256 * 2;
  u16* Whh_b  = (u16*)p;  p += (size_t)2048 * 512 * 2;
  u16* Wag_b  = (u16*)p;  p += (size_t)256 * 512 * 2;
  float* bc   = (float*)p; p += (size_t)2048 * 4;
  p = (char*)(((size_t)p + 255) & ~(size_t)255);
  u16* emb_b = (u16*)p;   p += (size_t)32768 * 256 * 2;   // 16 MB
  u16* xgT   = (u16*)p;   p += (size_t)32768 * 2048 * 2;  // 128 MB, [t][b][2048]
  u16* hs    = (u16*)p;   p += (size_t)32768 * 512 * 2;   // 32 MB
  u16* h2    = (u16*)p;   p += (size_t)2 * 512 * 512 * 2; // 1 MB
  u32* ctr   = (u32*)p;   p += (size_t)64 * 8 * 32 * 4;   // 64 KB padded

  cvt_f32_bf16<<<256, 256, 0, stream>>>(W_emb, Wemb_b, 256 * 1024);
  cvt_f32_bf16<<<512, 256, 0, stream>>>(W_ih, Wih_b, 2048 * 256);
  cvt_f32_bf16<<<1024, 256, 0, stream>>>(W_hh, Whh_b, 2048 * 512);
  cvt_f32_bf16<<<128, 256, 0, stream>>>(W_ag, Wag_b, 256 * 512);
  bias_add<<<8, 256, 0, stream>>>(b_ih, b_hh, bc, 2048);
  zero_u32<<<64, 256, 0, stream>>>(ctr, 64 * 8 * 32);

  // emb[B*T,256] = msg[B*T,1024] @ W_emb^T + b_emb   (bf16 out)
  gemm_bt<1, 1, 0><<<dim3(256, 2), 256, 0, stream>>>(msg, Wemb_b, b_emb, emb_b,
                                                     1024, 1024, 1024, 256);
  // xgT[t][b][2048] = (emb @ W_ih^T + bc), rows permuted (b*64+t -> t*512+b)
  gemm_bt<0, 1, 1><<<dim3(256, 16), 256, 0, stream>>>(emb_b, Wih_b, bc, xgT,
                                                      256, 256, 256, 2048);
  // persistent recurrence: 64 steps in one kernel
  lstm_persist<<<256, 256, 0, stream>>>(xgT, Whh_b, h2, hs, ctr);
  // out[B*T,256] = hs @ W_agent^T + b_agent          (f32 out)
  gemm_bt<0, 0, 0><<<dim3(256, 2), 256, 0, stream>>>(hs, Wag_b, b_ag, out,
                                                     512, 512, 512, 256);
}